// Round 1
// baseline (2775.100 us; speedup 1.0000x reference)
//
#include <hip/hip_runtime.h>
#include <math.h>

// SuperVoxel critical-component loss on MI355X.
// mean( (0.5 + 0.25*neg + 0.25*pos) * bce_loss )
//   neg: pixel in target-fg whose 4-connected target component contains a
//        pixel where pred-fg is false.
//   pos: symmetric with pred components vs target-fg.
// Implemented with lock-free union-find (ECL-CC style) per phase, flag bit
// OR'd into component roots, fused loss+reduction.

#define HH 1024
#define WW 1024
#define IMGPIX (HH * WW)
#define NB_TOTAL 16
#define FLAGBIT 0x40000000
#define IDXMASK 0x3FFFFFFF

__device__ __forceinline__ int findRoot(const int* p, int i) {
    int r = p[i];
    while (r != p[r]) r = p[r];
    return r;
}

__device__ __forceinline__ void unite(int* p, int a, int b) {
    int ra = findRoot(p, a);
    int rb = findRoot(p, b);
    while (ra != rb) {
        if (ra < rb) { int t = ra; ra = rb; rb = t; }  // ra > rb: hook big under small
        int prev = atomicCAS(&p[ra], ra, rb);
        if (prev == ra || prev == rb) break;
        ra = findRoot(p, prev);
        rb = findRoot(p, rb);
    }
}

__global__ void k_zero_acc(double* acc) {
    if (threadIdx.x == 0 && blockIdx.x == 0) *acc = 0.0;
}

__global__ void k_init(int* __restrict__ parent, int n) {
    int i = blockIdx.x * blockDim.x + threadIdx.x;
    if (i < n) parent[i] = i;
}

// Union right & down neighbors within each image for fg pixels of src (> thr).
__global__ void k_link(int* __restrict__ parent, const float* __restrict__ src,
                       float thr, long gbase, int n) {
    int i = blockIdx.x * blockDim.x + threadIdx.x;
    if (i >= n) return;
    float v = src[gbase + i];
    if (!(v > thr)) return;
    int x = i % WW;
    int y = (i / WW) % HH;
    if (x + 1 < WW && src[gbase + i + 1] > thr) unite(parent, i, i + 1);
    if (y + 1 < HH && src[gbase + i + WW] > thr) unite(parent, i, i + WW);
}

__global__ void k_compress(int* __restrict__ parent, int n) {
    int i = blockIdx.x * blockDim.x + threadIdx.x;
    if (i >= n) return;
    parent[i] = findRoot(parent, i);
}

// Mistake pixels (fgA && !fgB) set FLAGBIT on their component root.
__global__ void k_flag(int* __restrict__ parent, const float* __restrict__ a,
                       float thrA, const float* __restrict__ b, float thrB,
                       long gbase, int n) {
    int i = blockIdx.x * blockDim.x + threadIdx.x;
    if (i >= n) return;
    long g = gbase + i;
    if (a[g] > thrA && !(b[g] > thrB)) {
        int r = parent[i] & IDXMASK;
        atomicOr(&parent[r], FLAGBIT);
    }
}

// Fused loss + weighted reduction. phase 0 also accumulates the 0.5*loss base.
__global__ void k_accum(const int* __restrict__ parent,
                        const float* __restrict__ preds,
                        const float* __restrict__ targets,
                        long gbase, int n, double* __restrict__ acc, int phase) {
    int i = blockIdx.x * blockDim.x + threadIdx.x;
    float c = 0.0f;
    if (i < n) {
        long g = gbase + i;
        float p = preds[g];
        float t = targets[g];
        float loss = fmaxf(p, 0.0f) - p * t + log1pf(expf(-fabsf(p)));
        if (phase == 0) c = 0.5f * loss;
        bool fgA = (phase == 0) ? (t > 0.0f) : (p > 0.5f);
        if (fgA) {
            int r = parent[i] & IDXMASK;
            if (parent[r] & FLAGBIT) c += 0.25f * loss;
        }
    }
    // block reduce (256 threads = 4 waves)
    double v = (double)c;
    #pragma unroll
    for (int off = 32; off > 0; off >>= 1) v += __shfl_down(v, off, 64);
    __shared__ double s[4];
    int lane = threadIdx.x & 63;
    int wid = threadIdx.x >> 6;
    if (lane == 0) s[wid] = v;
    __syncthreads();
    if (threadIdx.x == 0) {
        double tot = s[0] + s[1] + s[2] + s[3];
        atomicAdd(acc, tot);
    }
}

__global__ void k_final(const double* __restrict__ acc, float* __restrict__ out,
                        double inv_n) {
    if (threadIdx.x == 0 && blockIdx.x == 0) out[0] = (float)(*acc * inv_n);
}

extern "C" void kernel_launch(void* const* d_in, const int* in_sizes, int n_in,
                              void* d_out, int out_size, void* d_ws, size_t ws_size,
                              hipStream_t stream) {
    const float* preds = (const float*)d_in[0];
    const float* targets = (const float*)d_in[1];
    float* out = (float*)d_out;

    double* acc = (double*)d_ws;
    int* parent = (int*)((char*)d_ws + 256);
    size_t avail = (ws_size > 256) ? ws_size - 256 : 0;
    int chunk = (int)(avail / ((size_t)IMGPIX * sizeof(int)));
    if (chunk < 1) chunk = 1;
    if (chunk > NB_TOTAL) chunk = NB_TOTAL;

    k_zero_acc<<<1, 1, 0, stream>>>(acc);

    for (int b0 = 0; b0 < NB_TOTAL; b0 += chunk) {
        int nb = (b0 + chunk <= NB_TOTAL) ? chunk : (NB_TOTAL - b0);
        int n = nb * IMGPIX;
        long gbase = (long)b0 * IMGPIX;
        int blocks = (n + 255) / 256;

        // phase 0 (neg): components of target-fg (t > 0), mistakes where !(p > 0.5)
        k_init<<<blocks, 256, 0, stream>>>(parent, n);
        k_link<<<blocks, 256, 0, stream>>>(parent, targets, 0.0f, gbase, n);
        k_compress<<<blocks, 256, 0, stream>>>(parent, n);
        k_flag<<<blocks, 256, 0, stream>>>(parent, targets, 0.0f, preds, 0.5f, gbase, n);
        k_accum<<<blocks, 256, 0, stream>>>(parent, preds, targets, gbase, n, acc, 0);

        // phase 1 (pos): components of pred-fg (p > 0.5), mistakes where !(t > 0)
        k_init<<<blocks, 256, 0, stream>>>(parent, n);
        k_link<<<blocks, 256, 0, stream>>>(parent, preds, 0.5f, gbase, n);
        k_compress<<<blocks, 256, 0, stream>>>(parent, n);
        k_flag<<<blocks, 256, 0, stream>>>(parent, preds, 0.5f, targets, 0.0f, gbase, n);
        k_accum<<<blocks, 256, 0, stream>>>(parent, preds, targets, gbase, n, acc, 1);
    }

    double inv_n = 1.0 / ((double)NB_TOTAL * (double)IMGPIX);
    k_final<<<1, 1, 0, stream>>>(acc, out, inv_n);
}

// Round 2
// 932.785 us; speedup vs baseline: 2.9751x; 2.9751x over previous
//
#include <hip/hip_runtime.h>
#include <math.h>

// SuperVoxel critical-component loss on MI355X.
// mean( (0.5 + 0.25*neg + 0.25*pos) * bce_loss )
// Union-find CCL per phase over bitmasks; flag bit on component roots;
// per-block partials (no contended atomics) + final reduce.

#define HH 1024
#define WW 1024
#define IMGPIX (HH * WW)
#define NB_TOTAL 16
#define FLAGBIT 0x40000000
#define IDXMASK 0x3FFFFFFF
#define NBLK 2048
#define NTHR 256

typedef unsigned long long u64;

__device__ __forceinline__ int findRootM(const int* __restrict__ p, int i) {
    int r = i;
    int pr = p[r] & IDXMASK;
    while (pr != r) { r = pr; pr = p[r] & IDXMASK; }
    return r;
}

__device__ __forceinline__ void unite(int* p, int a, int b) {
    int ra = findRootM(p, a);
    int rb = findRootM(p, b);
    while (ra != rb) {
        if (ra < rb) { int t = ra; ra = rb; rb = t; }  // hook larger index under smaller
        int prev = atomicCAS(&p[ra], ra, rb);
        if (prev == ra) return;
        ra = findRootM(p, prev & IDXMASK);
        rb = findRootM(p, rb);
    }
}

__global__ void k_zero(double* __restrict__ part) {
    part[blockIdx.x * blockDim.x + threadIdx.x] = 0.0;
}

// Ballot foreground masks: maskP = preds > 0.5, maskT = targets > 0.
__global__ void k_mask(const float* __restrict__ preds, const float* __restrict__ targets,
                       long gbase, int n, u64* __restrict__ mP, u64* __restrict__ mT) {
    int stride = gridDim.x * blockDim.x;
    for (int i = blockIdx.x * blockDim.x + threadIdx.x; i < n; i += stride) {
        float p = preds[gbase + i];
        float t = targets[gbase + i];
        u64 bp = __ballot(p > 0.5f);
        u64 bt = __ballot(t > 0.0f);
        if ((i & 63) == 0) { mP[i >> 6] = bp; mT[i >> 6] = bt; }
    }
}

// Init parent as left-chains within row runs (atomic-free horizontal merging).
__global__ void k_init(int* __restrict__ parent, const u64* __restrict__ m, int n) {
    int stride = gridDim.x * blockDim.x;
    for (int i = blockIdx.x * blockDim.x + threadIdx.x; i < n; i += stride) {
        int wv = i >> 6, lane = i & 63;
        u64 w = m[wv];
        int par = i;
        if ((w >> lane) & 1) {
            bool leftfg;
            if (lane > 0) {
                leftfg = (w >> (lane - 1)) & 1;
            } else {
                int x = i & (WW - 1);
                leftfg = (x > 0) ? ((m[wv - 1] >> 63) & 1) : false;
            }
            if (leftfg) par = i - 1;
        }
        parent[i] = par;
    }
}

// Unite vertical edges only (horizontal covered by left-chains). Skip when the
// left-adjacent column pair is also fg-fg (that column does the unite).
__global__ void k_link(int* __restrict__ parent, const u64* __restrict__ m, int n) {
    int stride = gridDim.x * blockDim.x;
    for (int i = blockIdx.x * blockDim.x + threadIdx.x; i < n; i += stride) {
        int yimg = (i >> 10) & (HH - 1);
        if (yimg == HH - 1) continue;
        int wv = i >> 6, lane = i & 63;
        u64 w0 = m[wv];
        if (!((w0 >> lane) & 1)) continue;
        u64 wd = m[wv + (WW / 64)];
        if (!((wd >> lane) & 1)) continue;
        // dedup: if (left, downleft) both fg, that pair's unite covers us
        int x = i & (WW - 1);
        if (x > 0) {
            bool lf, dlf;
            if (lane > 0) { lf = (w0 >> (lane - 1)) & 1; dlf = (wd >> (lane - 1)) & 1; }
            else { lf = (m[wv - 1] >> 63) & 1; dlf = (m[wv + (WW / 64) - 1] >> 63) & 1; }
            if (lf && dlf) continue;
        }
        unite(parent, i, i + WW);
    }
}

// Fused path-compress + flag: for fg-of-A pixels, compress to root; if pixel is
// a mistake (not fg-of-B), set FLAGBIT on the root (pre-check to skip atomics).
__global__ void k_cflag(int* __restrict__ parent, const u64* __restrict__ mA,
                        const u64* __restrict__ mB, int n) {
    int stride = gridDim.x * blockDim.x;
    for (int i = blockIdx.x * blockDim.x + threadIdx.x; i < n; i += stride) {
        int wv = i >> 6, lane = i & 63;
        u64 wa = mA[wv];
        if (!((wa >> lane) & 1)) continue;
        int r = findRootM(parent, i);
        if (r != i) parent[i] = r;  // plain store; only roots receive atomicOr
        if (!((mB[wv] >> lane) & 1)) {
            if (!(parent[r] & FLAGBIT)) atomicOr(&parent[r], FLAGBIT);
        }
    }
}

// Fused loss + weighted accumulation into per-block partials (no atomics).
__global__ void k_accum(const int* __restrict__ parent, const u64* __restrict__ mA,
                        const float* __restrict__ preds, const float* __restrict__ targets,
                        long gbase, int n, double* __restrict__ part, int phase) {
    int stride = gridDim.x * blockDim.x;
    double local = 0.0;
    for (int i = blockIdx.x * blockDim.x + threadIdx.x; i < n; i += stride) {
        float p = preds[gbase + i];
        float t = targets[gbase + i];
        float loss = fmaxf(p, 0.0f) - p * t + log1pf(expf(-fabsf(p)));
        float c = (phase == 0) ? 0.5f * loss : 0.0f;
        if ((mA[i >> 6] >> (i & 63)) & 1) {
            int r = parent[i] & IDXMASK;
            if (parent[r] & FLAGBIT) c += 0.25f * loss;
        }
        local += c;
    }
    #pragma unroll
    for (int off = 32; off > 0; off >>= 1) local += __shfl_down(local, off, 64);
    __shared__ double s[NTHR / 64];
    int lane = threadIdx.x & 63, wid = threadIdx.x >> 6;
    if (lane == 0) s[wid] = local;
    __syncthreads();
    if (threadIdx.x == 0) {
        double tot = 0.0;
        #pragma unroll
        for (int w = 0; w < NTHR / 64; ++w) tot += s[w];
        part[blockIdx.x] += tot;  // serialized dispatches: plain += is safe & deterministic
    }
}

__global__ void k_final(const double* __restrict__ part, float* __restrict__ out, double inv_n) {
    double v = 0.0;
    for (int i = threadIdx.x; i < NBLK; i += blockDim.x) v += part[i];
    #pragma unroll
    for (int off = 32; off > 0; off >>= 1) v += __shfl_down(v, off, 64);
    __shared__ double s[NTHR / 64];
    int lane = threadIdx.x & 63, wid = threadIdx.x >> 6;
    if (lane == 0) s[wid] = v;
    __syncthreads();
    if (threadIdx.x == 0) {
        double tot = 0.0;
        #pragma unroll
        for (int w = 0; w < NTHR / 64; ++w) tot += s[w];
        out[0] = (float)(tot * inv_n);
    }
}

extern "C" void kernel_launch(void* const* d_in, const int* in_sizes, int n_in,
                              void* d_out, int out_size, void* d_ws, size_t ws_size,
                              hipStream_t stream) {
    const float* preds = (const float*)d_in[0];
    const float* targets = (const float*)d_in[1];
    float* out = (float*)d_out;

    // ws layout: partials | maskP | maskT | parent (chunked over images if tight)
    double* part = (double*)d_ws;
    char* base = (char*)d_ws + NBLK * sizeof(double);
    size_t avail = (ws_size > NBLK * sizeof(double)) ? ws_size - NBLK * sizeof(double) : 0;
    const size_t words_per_img = IMGPIX / 64;                        // 16384
    const size_t per_img = 2 * words_per_img * sizeof(u64) + (size_t)IMGPIX * sizeof(int);
    int chunk = (int)(avail / per_img);
    if (chunk < 1) chunk = 1;
    if (chunk > NB_TOTAL) chunk = NB_TOTAL;

    u64* mP = (u64*)base;
    u64* mT = mP + (size_t)chunk * words_per_img;
    int* parent = (int*)(mT + (size_t)chunk * words_per_img);

    k_zero<<<NBLK / NTHR, NTHR, 0, stream>>>(part);

    for (int b0 = 0; b0 < NB_TOTAL; b0 += chunk) {
        int nb = (b0 + chunk <= NB_TOTAL) ? chunk : (NB_TOTAL - b0);
        int n = nb * IMGPIX;
        long gbase = (long)b0 * IMGPIX;

        k_mask<<<NBLK, NTHR, 0, stream>>>(preds, targets, gbase, n, mP, mT);

        // phase 0 (neg): components of target-fg, mistakes where pred-fg false
        k_init<<<NBLK, NTHR, 0, stream>>>(parent, mT, n);
        k_link<<<NBLK, NTHR, 0, stream>>>(parent, mT, n);
        k_cflag<<<NBLK, NTHR, 0, stream>>>(parent, mT, mP, n);
        k_accum<<<NBLK, NTHR, 0, stream>>>(parent, mT, preds, targets, gbase, n, part, 0);

        // phase 1 (pos): components of pred-fg, mistakes where target-fg false
        k_init<<<NBLK, NTHR, 0, stream>>>(parent, mP, n);
        k_link<<<NBLK, NTHR, 0, stream>>>(parent, mP, n);
        k_cflag<<<NBLK, NTHR, 0, stream>>>(parent, mP, mT, n);
        k_accum<<<NBLK, NTHR, 0, stream>>>(parent, mP, preds, targets, gbase, n, part, 1);
    }

    double inv_n = 1.0 / ((double)NB_TOTAL * (double)IMGPIX);
    k_final<<<1, NTHR, 0, stream>>>(part, out, inv_n);
}

// Round 3
// 576.162 us; speedup vs baseline: 4.8165x; 1.6190x over previous
//
#include <hip/hip_runtime.h>
#include <math.h>

// SuperVoxel critical-component loss on MI355X.
// mean( (0.5 + 0.25*neg + 0.25*pos) * bce_loss )
// Two-level CCL: per-tile union-find in LDS (64x64 tiles), global union only
// on tile-boundary edges; flag bit on component roots; fused compress+flag and
// fused dual-phase loss accumulation into per-block partials.

#define HH 1024
#define WW 1024
#define IMGPIX (HH * WW)
#define NB_TOTAL 16
#define FLAGBIT 0x40000000
#define IDXMASK 0x3FFFFFFF
#define NBLK 2048
#define NTHR 256
#define TSZ 64
#define TILES_X (WW / TSZ)            // 16
#define TILES_PER_IMG (TILES_X * (HH / TSZ))  // 256
#define WPI (IMGPIX / 64)             // mask words per image: 16384

typedef unsigned long long u64;

// ---------- global union-find ----------
__device__ __forceinline__ int findRootG(const int* __restrict__ p, int i) {
    int r = i;
    int pr = p[r] & IDXMASK;
    while (pr != r) { r = pr; pr = p[r] & IDXMASK; }
    return r;
}

__device__ __forceinline__ void uniteG(int* p, int a, int b) {
    int ra = findRootG(p, a);
    int rb = findRootG(p, b);
    while (ra != rb) {
        if (ra < rb) { int t = ra; ra = rb; rb = t; }  // hook larger under smaller
        int prev = atomicCAS(&p[ra], ra, rb);
        if (prev == ra) return;
        ra = findRootG(p, prev & IDXMASK);
        rb = findRootG(p, rb);
    }
}

// ---------- LDS union-find ----------
__device__ __forceinline__ int findRootL(volatile int* lab, int i) {
    int r = lab[i];
    while (r != lab[r]) r = lab[r];
    return r;
}

__device__ __forceinline__ void uniteL(int* lab, int a, int b) {
    volatile int* vl = lab;
    int ra = findRootL(vl, a);
    int rb = findRootL(vl, b);
    while (ra != rb) {
        if (ra < rb) { int t = ra; ra = rb; rb = t; }
        int prev = atomicCAS(&lab[ra], ra, rb);
        if (prev == ra) return;
        ra = findRootL(vl, prev);
        rb = findRootL(vl, rb);
    }
}

__global__ void k_zero(double* __restrict__ part) {
    part[blockIdx.x * blockDim.x + threadIdx.x] = 0.0;
}

// One block = one 64x64 tile; both phases (targets then preds) in sequence.
// Local CCL entirely in LDS; writes parent (pixel -> tile-local-root, global
// pixel index) and the foreground bitmask.
__global__ void k_local(const float* __restrict__ preds, const float* __restrict__ targets,
                        long gbase, u64* __restrict__ mP, u64* __restrict__ mT,
                        int* __restrict__ parentP, int* __restrict__ parentT) {
    __shared__ int lab[TSZ * TSZ];
    __shared__ u64 rowm[TSZ];

    const int img = blockIdx.x / TILES_PER_IMG;
    const int tile = blockIdx.x % TILES_PER_IMG;
    const int ty = tile / TILES_X, tx = tile % TILES_X;
    const int w = threadIdx.x >> 6, lane = threadIdx.x & 63;
    const long imgpix = (long)img * IMGPIX;
    const int tilebase = (ty * TSZ) * WW + tx * TSZ;  // pixel offset within image

    for (int ph = 0; ph < 2; ++ph) {
        const float* src = ph ? preds : targets;
        const float thr = ph ? 0.5f : 0.0f;
        u64* mask = ph ? mP : mT;
        int* parent = ph ? parentP : parentT;

        // load + ballot row masks
        #pragma unroll 4
        for (int j = 0; j < 16; ++j) {
            int r = w * 16 + j;
            float v = src[gbase + imgpix + tilebase + (long)r * WW + lane];
            u64 bm = __ballot(v > thr);
            if (lane == 0) {
                rowm[r] = bm;
                mask[img * WPI + ((ty * TSZ + r) * TILES_X + tx)] = bm;
            }
        }
        __syncthreads();

        // init: left-chains within rows (tile-local)
        #pragma unroll 4
        for (int j = 0; j < 16; ++j) {
            int r = w * 16 + j;
            int li = r * TSZ + lane;
            u64 m = rowm[r];
            int par = li;
            if (((m >> lane) & 1) && lane > 0 && ((m >> (lane - 1)) & 1)) par = li - 1;
            lab[li] = par;
        }
        __syncthreads();

        // vertical unions (dedup: left column pair covers us)
        #pragma unroll 4
        for (int j = 0; j < 16; ++j) {
            int r = w * 16 + j;
            if (r >= TSZ - 1) continue;
            u64 m0 = rowm[r], m1 = rowm[r + 1];
            if (((m0 >> lane) & 1) && ((m1 >> lane) & 1)) {
                bool skip = (lane > 0) && ((m0 >> (lane - 1)) & 1) && ((m1 >> (lane - 1)) & 1);
                if (!skip) uniteL(lab, r * TSZ + lane, (r + 1) * TSZ + lane);
            }
        }
        __syncthreads();

        // compress + write global parent (full-line coalesced writes)
        #pragma unroll 4
        for (int j = 0; j < 16; ++j) {
            int r = w * 16 + j;
            int li = r * TSZ + lane;
            int gp = (int)imgpix + tilebase + r * WW + lane;
            if ((rowm[r] >> lane) & 1) {
                int rt = findRootL(lab, li);
                gp = (int)imgpix + tilebase + (rt >> 6) * WW + (rt & 63);
                parent[(int)imgpix + tilebase + r * WW + lane] = gp;
            } else {
                parent[(int)imgpix + tilebase + r * WW + lane] = gp;  // self (unused)
            }
        }
        __syncthreads();  // rowm/lab reused next phase
    }
}

// Global unions across tile boundaries only (~30720 edges/img/phase).
__global__ void k_boundary(const u64* __restrict__ mP, const u64* __restrict__ mT,
                           int* __restrict__ parentP, int* __restrict__ parentT,
                           int nb) {
    const int per_img = 2 * 15 * WW;  // 30720
    long total = (long)nb * per_img * 2;
    long stride = (long)gridDim.x * blockDim.x;
    for (long e = blockIdx.x * (long)blockDim.x + threadIdx.x; e < total; e += stride) {
        int ph = (int)(e & 1);
        long e2 = e >> 1;
        int img = (int)(e2 / per_img);
        int k = (int)(e2 % per_img);
        int a, b;
        if (k < 15 * WW) {            // horizontal cut: (y, x)-(y+1, x), y = 64c+63
            int cut = k >> 10, x = k & (WW - 1);
            a = (cut * TSZ + 63) * WW + x;
            b = a + WW;
        } else {                      // vertical cut: (y, x)-(y, x+1), x = 64c+63
            int k2 = k - 15 * WW;
            int cut = k2 >> 10, y = k2 & (HH - 1);
            a = y * WW + cut * TSZ + 63;
            b = a + 1;
        }
        const u64* m = ph ? mP : mT;
        int* parent = ph ? parentP : parentT;
        long wbase = (long)img * WPI;
        bool fa = (m[wbase + (a >> 6)] >> (a & 63)) & 1;
        bool fb = (m[wbase + (b >> 6)] >> (b & 63)) & 1;
        if (fa && fb) uniteG(parent, img * IMGPIX + a, img * IMGPIX + b);
    }
}

// Fused path-compress + mistake flagging for both phases.
__global__ void k_cflag(int* __restrict__ parentT, int* __restrict__ parentP,
                        const u64* __restrict__ mT, const u64* __restrict__ mP, int n) {
    int stride = gridDim.x * blockDim.x;
    for (int i = blockIdx.x * blockDim.x + threadIdx.x; i < n; i += stride) {
        int wv = i >> 6, lane = i & 63;
        bool ft = (mT[wv] >> lane) & 1;
        bool fp = (mP[wv] >> lane) & 1;
        if (ft) {
            int r = findRootG(parentT, i);
            if (r != i) parentT[i] = r;
            if (!fp && !(parentT[r] & FLAGBIT)) atomicOr(&parentT[r], FLAGBIT);
        }
        if (fp) {
            int r = findRootG(parentP, i);
            if (r != i) parentP[i] = r;
            if (!ft && !(parentP[r] & FLAGBIT)) atomicOr(&parentP[r], FLAGBIT);
        }
    }
}

// Fused loss + both weight terms, per-block partials (no atomics).
__global__ void k_accum(const int* __restrict__ parentT, const int* __restrict__ parentP,
                        const float* __restrict__ preds, const float* __restrict__ targets,
                        long gbase, int n, double* __restrict__ part) {
    int stride = gridDim.x * blockDim.x;
    double local = 0.0;
    for (int i = blockIdx.x * blockDim.x + threadIdx.x; i < n; i += stride) {
        float p = preds[gbase + i];
        float t = targets[gbase + i];
        float loss = fmaxf(p, 0.0f) - p * t + log1pf(expf(-fabsf(p)));
        float wgt = 0.5f;
        if (t > 0.0f) {
            int r = parentT[i] & IDXMASK;
            if (parentT[r] & FLAGBIT) wgt += 0.25f;
        }
        if (p > 0.5f) {
            int r = parentP[i] & IDXMASK;
            if (parentP[r] & FLAGBIT) wgt += 0.25f;
        }
        local += (double)(wgt * loss);
    }
    #pragma unroll
    for (int off = 32; off > 0; off >>= 1) local += __shfl_down(local, off, 64);
    __shared__ double s[NTHR / 64];
    int lane = threadIdx.x & 63, wid = threadIdx.x >> 6;
    if (lane == 0) s[wid] = local;
    __syncthreads();
    if (threadIdx.x == 0) {
        double tot = 0.0;
        #pragma unroll
        for (int w = 0; w < NTHR / 64; ++w) tot += s[w];
        part[blockIdx.x] += tot;  // zeroed each call; chunks accumulate serially
    }
}

__global__ void k_final(const double* __restrict__ part, float* __restrict__ out, double inv_n) {
    double v = 0.0;
    for (int i = threadIdx.x; i < NBLK; i += blockDim.x) v += part[i];
    #pragma unroll
    for (int off = 32; off > 0; off >>= 1) v += __shfl_down(v, off, 64);
    __shared__ double s[NTHR / 64];
    int lane = threadIdx.x & 63, wid = threadIdx.x >> 6;
    if (lane == 0) s[wid] = v;
    __syncthreads();
    if (threadIdx.x == 0) {
        double tot = 0.0;
        #pragma unroll
        for (int w = 0; w < NTHR / 64; ++w) tot += s[w];
        out[0] = (float)(tot * inv_n);
    }
}

extern "C" void kernel_launch(void* const* d_in, const int* in_sizes, int n_in,
                              void* d_out, int out_size, void* d_ws, size_t ws_size,
                              hipStream_t stream) {
    const float* preds = (const float*)d_in[0];
    const float* targets = (const float*)d_in[1];
    float* out = (float*)d_out;

    // ws: partials | maskT | maskP | parentT | parentP   (chunked over images)
    double* part = (double*)d_ws;
    char* base = (char*)d_ws + NBLK * sizeof(double);
    size_t avail = (ws_size > NBLK * sizeof(double)) ? ws_size - NBLK * sizeof(double) : 0;
    const size_t per_img = 2 * WPI * sizeof(u64) + 2 * (size_t)IMGPIX * sizeof(int);
    int chunk = (int)(avail / per_img);
    if (chunk < 1) chunk = 1;
    if (chunk > NB_TOTAL) chunk = NB_TOTAL;

    u64* mT = (u64*)base;
    u64* mP = mT + (size_t)chunk * WPI;
    int* parentT = (int*)(mP + (size_t)chunk * WPI);
    int* parentP = parentT + (size_t)chunk * IMGPIX;

    k_zero<<<NBLK / NTHR, NTHR, 0, stream>>>(part);

    for (int b0 = 0; b0 < NB_TOTAL; b0 += chunk) {
        int nb = (b0 + chunk <= NB_TOTAL) ? chunk : (NB_TOTAL - b0);
        int n = nb * IMGPIX;
        long gbase = (long)b0 * IMGPIX;

        k_local<<<nb * TILES_PER_IMG, NTHR, 0, stream>>>(preds, targets, gbase, mP, mT, parentP, parentT);
        k_boundary<<<512, NTHR, 0, stream>>>(mP, mT, parentP, parentT, nb);
        k_cflag<<<NBLK, NTHR, 0, stream>>>(parentT, parentP, mT, mP, n);
        k_accum<<<NBLK, NTHR, 0, stream>>>(parentT, parentP, preds, targets, gbase, n, part);
    }

    double inv_n = 1.0 / ((double)NB_TOTAL * (double)IMGPIX);
    k_final<<<1, NTHR, 0, stream>>>(part, out, inv_n);
}